// Round 4
// baseline (479.986 us; speedup 1.0000x reference)
//
#include <hip/hip_runtime.h>
#include <hip/hip_bf16.h>
#include <stdint.h>

// Problem constants
#define S 1024
#define DMODEL 768
#define NH 12
#define DK 64
#define BB 4
#define BH 48      // BB*NH
#define M4 4096    // BB*S

typedef __attribute__((ext_vector_type(8))) short bf16x8;
typedef __attribute__((ext_vector_type(4))) float f32x4;
typedef __attribute__((ext_vector_type(4))) _Float16 f16x4;

static __device__ __forceinline__ unsigned short f2bf(float f) {
  unsigned int u = __float_as_uint(f);
  unsigned int r = u + 0x7FFFu + ((u >> 16) & 1u);   // RNE
  return (unsigned short)(r >> 16);
}
static __device__ __forceinline__ unsigned int pk2(float a, float b) {
  return (unsigned int)f2bf(a) | ((unsigned int)f2bf(b) << 16);
}
static __device__ __forceinline__ bf16x8 ldfrag(const unsigned short* p) {
  uint4 q = *reinterpret_cast<const uint4*>(p);
  return __builtin_bit_cast(bf16x8, q);
}
static __device__ __forceinline__ unsigned short h2u(_Float16 h) {
  return __builtin_bit_cast(unsigned short, h);
}

// ---------------- W [k][n] f32 -> Wt [n][k] bf16 (768x768) ----------------
__global__ __launch_bounds__(256) void k_transpose(const float* w0, const float* w1, const float* w2,
                                                   unsigned short* o0, unsigned short* o1, unsigned short* o2) {
  const float* in = blockIdx.z == 0 ? w0 : (blockIdx.z == 1 ? w1 : w2);
  unsigned short* out = blockIdx.z == 0 ? o0 : (blockIdx.z == 1 ? o1 : o2);
  __shared__ float tile[32][33];
  int n0 = blockIdx.x * 32, k0 = blockIdx.y * 32;
  int tid = threadIdx.x;
  int r = tid >> 3, c = (tid & 7) * 4;
  float4 v = *reinterpret_cast<const float4*>(in + (size_t)(k0 + r) * DMODEL + n0 + c);
  tile[r][c] = v.x; tile[r][c + 1] = v.y; tile[r][c + 2] = v.z; tile[r][c + 3] = v.w;
  __syncthreads();
  ushort4 o;
  o.x = f2bf(tile[c + 0][r]);
  o.y = f2bf(tile[c + 1][r]);
  o.z = f2bf(tile[c + 2][r]);
  o.w = f2bf(tile[c + 3][r]);
  *reinterpret_cast<ushort4*>(out + (size_t)(n0 + r) * DMODEL + k0 + c) = o;
}

// ---------------- mask [BH][t][s] int32 -> bit arrays (word-major), both orientations ----------------
// mp1[bh][wd=t>>5][s] bit(t&31) = mask[t][s]   (path0: rows s, cols t)
// mp2[bh][wd=s>>5][t] bit(s&31) = mask[t][s]   (path1: rows t, cols s)
__global__ __launch_bounds__(256) void k_pack(const int* __restrict__ mask,
                                              unsigned int* __restrict__ mp1,
                                              unsigned int* __restrict__ mp2) {
  int bh = blockIdx.y;
  int w = threadIdx.x >> 6, lane = threadIdx.x & 63;
  int tile = blockIdx.x * 4 + w;          // 0..255
  int ti = tile >> 4, tj = tile & 15;
  int t0 = ti * 64, s0 = tj * 64;
  const int* mb = mask + (size_t)bh * S * S;
  unsigned long long rowword = 0;
#pragma unroll 8
  for (int r = 0; r < 64; ++r) {
    int v = mb[(size_t)(t0 + r) * S + s0 + lane];
    unsigned long long b = __ballot(v != 0);
    if (lane == r) rowword = b;           // lane r holds bits over s for row t0+r
  }
  unsigned int* p2 = mp2 + (size_t)bh * 32 * S;
  p2[((s0 >> 5) + 0) * S + t0 + lane] = (unsigned int)rowword;
  p2[((s0 >> 5) + 1) * S + t0 + lane] = (unsigned int)(rowword >> 32);
  unsigned long long colword = 0;
#pragma unroll
  for (int s = 0; s < 64; ++s) {
    unsigned long long b = __ballot((rowword >> s) & 1ull);
    if (lane == s) colword = b;           // lane s holds bits over t for col s0+s
  }
  unsigned int* p1 = mp1 + (size_t)bh * 32 * S;
  p1[((t0 >> 5) + 0) * S + s0 + lane] = (unsigned int)colword;
  p1[((t0 >> 5) + 1) * S + s0 + lane] = (unsigned int)(colword >> 32);
}

// ---------------- 128x128-tile bf16 GEMM: C[4096x768] = A[4096x768] * Bt^T ----------------
// mode 0: A is f32 (converted during staging); writes Q/K [BH][S][DK] bf16 AND
//         transposed [BH][DK][S] f16 (coalesced via in-register MFMA transpose).
// mode 1: A is bf16; writes f32 [4096][768] (pre-LayerNorm).
__global__ __launch_bounds__(256, 2) void k_gemm128(
    int mode,
    const float* __restrict__ Af0, const float* __restrict__ Af1,
    const unsigned short* __restrict__ Ab0, const unsigned short* __restrict__ Ab1,
    const unsigned short* __restrict__ Bt0, const unsigned short* __restrict__ Bt1,
    unsigned short* __restrict__ oQ0, unsigned short* __restrict__ oQ1,
    unsigned short* __restrict__ oT0, unsigned short* __restrict__ oT1,
    float* __restrict__ oF0, float* __restrict__ oF1) {
  const float* Af = blockIdx.z ? Af1 : Af0;
  const unsigned short* Ab = blockIdx.z ? Ab1 : Ab0;
  const unsigned short* Bt = blockIdx.z ? Bt1 : Bt0;
  __shared__ __align__(16) unsigned short As[128 * 72];   // 18432 B
  __shared__ __align__(16) unsigned short Bs[128 * 72];   // 18432 B
  int tid = threadIdx.x;
  int m0 = blockIdx.x * 128, n0 = blockIdx.y * 128;
  int w = tid >> 6, lane = tid & 63, lane15 = lane & 15, quad = lane >> 4;
  int row0 = (w >> 1) * 64, col0 = (w & 1) * 64;
  f32x4 acc[4][4] = {};
  int sr = tid >> 2, sc = (tid & 3) * 16;
  // B prefetch (always bf16)
  const unsigned short* gB0 = Bt + (size_t)(n0 + sr) * DMODEL + sc;
  const unsigned short* gB1 = Bt + (size_t)(n0 + 64 + sr) * DMODEL + sc;
  uint4 vb[2][2];
  vb[0][0] = *reinterpret_cast<const uint4*>(gB0);
  vb[0][1] = *reinterpret_cast<const uint4*>(gB0 + 8);
  vb[1][0] = *reinterpret_cast<const uint4*>(gB1);
  vb[1][1] = *reinterpret_cast<const uint4*>(gB1 + 8);
  // A prefetch (f32 or bf16)
  const float* gAf0 = Af + (size_t)(m0 + sr) * DMODEL + sc;
  const float* gAf1 = Af + (size_t)(m0 + 64 + sr) * DMODEL + sc;
  const unsigned short* gAb0 = Ab + (size_t)(m0 + sr) * DMODEL + sc;
  const unsigned short* gAb1 = Ab + (size_t)(m0 + 64 + sr) * DMODEL + sc;
  float4 fa[2][4];
  uint4 va[2][2];
  if (mode == 0) {
#pragma unroll
    for (int g = 0; g < 4; ++g) fa[0][g] = *reinterpret_cast<const float4*>(gAf0 + g * 4);
#pragma unroll
    for (int g = 0; g < 4; ++g) fa[1][g] = *reinterpret_cast<const float4*>(gAf1 + g * 4);
  } else {
    va[0][0] = *reinterpret_cast<const uint4*>(gAb0);
    va[0][1] = *reinterpret_cast<const uint4*>(gAb0 + 8);
    va[1][0] = *reinterpret_cast<const uint4*>(gAb1);
    va[1][1] = *reinterpret_cast<const uint4*>(gAb1 + 8);
  }
  for (int kc = 0; kc < 12; ++kc) {
    __syncthreads();   // prior iter frag reads complete
    if (mode == 0) {
#pragma unroll
      for (int h2 = 0; h2 < 2; ++h2) {
        uint4 u0, u1;
        u0.x = pk2(fa[h2][0].x, fa[h2][0].y); u0.y = pk2(fa[h2][0].z, fa[h2][0].w);
        u0.z = pk2(fa[h2][1].x, fa[h2][1].y); u0.w = pk2(fa[h2][1].z, fa[h2][1].w);
        u1.x = pk2(fa[h2][2].x, fa[h2][2].y); u1.y = pk2(fa[h2][2].z, fa[h2][2].w);
        u1.z = pk2(fa[h2][3].x, fa[h2][3].y); u1.w = pk2(fa[h2][3].z, fa[h2][3].w);
        *reinterpret_cast<uint4*>(&As[(h2 * 64 + sr) * 72 + sc]) = u0;
        *reinterpret_cast<uint4*>(&As[(h2 * 64 + sr) * 72 + sc + 8]) = u1;
      }
    } else {
#pragma unroll
      for (int h2 = 0; h2 < 2; ++h2) {
        *reinterpret_cast<uint4*>(&As[(h2 * 64 + sr) * 72 + sc]) = va[h2][0];
        *reinterpret_cast<uint4*>(&As[(h2 * 64 + sr) * 72 + sc + 8]) = va[h2][1];
      }
    }
#pragma unroll
    for (int h2 = 0; h2 < 2; ++h2) {
      *reinterpret_cast<uint4*>(&Bs[(h2 * 64 + sr) * 72 + sc]) = vb[h2][0];
      *reinterpret_cast<uint4*>(&Bs[(h2 * 64 + sr) * 72 + sc + 8]) = vb[h2][1];
    }
    if (kc < 11) {
      int k0 = (kc + 1) * 64;
      if (mode == 0) {
#pragma unroll
        for (int g = 0; g < 4; ++g) fa[0][g] = *reinterpret_cast<const float4*>(gAf0 + k0 + g * 4);
#pragma unroll
        for (int g = 0; g < 4; ++g) fa[1][g] = *reinterpret_cast<const float4*>(gAf1 + k0 + g * 4);
      } else {
        va[0][0] = *reinterpret_cast<const uint4*>(gAb0 + k0);
        va[0][1] = *reinterpret_cast<const uint4*>(gAb0 + k0 + 8);
        va[1][0] = *reinterpret_cast<const uint4*>(gAb1 + k0);
        va[1][1] = *reinterpret_cast<const uint4*>(gAb1 + k0 + 8);
      }
      vb[0][0] = *reinterpret_cast<const uint4*>(gB0 + k0);
      vb[0][1] = *reinterpret_cast<const uint4*>(gB0 + k0 + 8);
      vb[1][0] = *reinterpret_cast<const uint4*>(gB1 + k0);
      vb[1][1] = *reinterpret_cast<const uint4*>(gB1 + k0 + 8);
    }
    __syncthreads();
#pragma unroll
    for (int ks = 0; ks < 2; ++ks) {
      int kk = ks * 32 + quad * 8;
      bf16x8 a[4], b[4];
#pragma unroll
      for (int i = 0; i < 4; ++i) a[i] = ldfrag(&As[(row0 + i * 16 + lane15) * 72 + kk]);
#pragma unroll
      for (int j = 0; j < 4; ++j) b[j] = ldfrag(&Bs[(col0 + j * 16 + lane15) * 72 + kk]);
#pragma unroll
      for (int i = 0; i < 4; ++i)
#pragma unroll
        for (int j = 0; j < 4; ++j)
          acc[i][j] = __builtin_amdgcn_mfma_f32_16x16x32_bf16(a[i], b[j], acc[i][j], 0, 0, 0);
    }
  }
  if (mode == 0) {
    unsigned short* out = blockIdx.z ? oQ1 : oQ0;
    unsigned short* outT = blockIdx.z ? oT1 : oT0;
    // identity B-frag for in-register 16x16 transpose
    f16x4 iden;
#pragma unroll
    for (int i = 0; i < 4; ++i) iden[i] = (_Float16)((quad * 4 + i) == lane15 ? 1.0f : 0.0f);
    f32x4 zero4 = {};
#pragma unroll
    for (int i = 0; i < 4; ++i)
#pragma unroll
      for (int j = 0; j < 4; ++j) {
        // normal-layout bf16 store (32B runs along d)
#pragma unroll
        for (int reg = 0; reg < 4; ++reg) {
          int m = m0 + row0 + i * 16 + quad * 4 + reg;
          int n = n0 + col0 + j * 16 + lane15;
          int b = m >> 10, s = m & 1023, h = n >> 6, d = n & 63;
          out[(((size_t)(b * NH + h)) * S + s) * DK + d] = f2bf(acc[i][j][reg]);
        }
        // transposed f16 store (32B runs along s)
        f16x4 cf;
#pragma unroll
        for (int reg = 0; reg < 4; ++reg) cf[reg] = (_Float16)acc[i][j][reg];
        f32x4 tq = __builtin_amdgcn_mfma_f32_16x16x16f16(cf, iden, zero4, 0, 0, 0);
#pragma unroll
        for (int reg = 0; reg < 4; ++reg) {
          int n = n0 + col0 + j * 16 + quad * 4 + reg;   // d-dimension
          int m = m0 + row0 + i * 16 + lane15;           // s-dimension
          int b = m >> 10, s = m & 1023, h = n >> 6, d = n & 63;
          outT[(((size_t)(b * NH + h)) * DK + d) * S + s] = h2u((_Float16)tq[reg]);
        }
      }
  } else {
    float* out = blockIdx.z ? oF1 : oF0;
#pragma unroll
    for (int i = 0; i < 4; ++i)
#pragma unroll
      for (int j = 0; j < 4; ++j)
#pragma unroll
        for (int reg = 0; reg < 4; ++reg) {
          int m = m0 + row0 + i * 16 + quad * 4 + reg;
          int n = n0 + col0 + j * 16 + lane15;
          out[(size_t)m * DMODEL + n] = acc[i][j][reg];
        }
  }
}

// ---------------- fused dual-path attention ----------------
// Block = (bh, path, 128 rows); wave w owns rows [s0b + w*32, +32) (2 groups of 16).
// Per 64-j chunk: YS/YTS staged in LDS (shared by 4 waves); scores in regs (x32 bf16);
// exp w/o max-subtraction (masked -> exact 0); P transposed in-register via
// mfma_16x16x16f16 identity trick (no P LDS); PV on f16 x16 MFMA, B-frags = b64 from YTS.
__global__ __launch_bounds__(256, 3) void k_attn(
    const unsigned short* __restrict__ Qb, const unsigned short* __restrict__ Kb,
    const unsigned short* __restrict__ QT, const unsigned short* __restrict__ KT,
    const unsigned int* __restrict__ mp1, const unsigned int* __restrict__ mp2,
    unsigned short* __restrict__ c1, unsigned short* __restrict__ c2) {
  int bh = blockIdx.y, path = blockIdx.z;
  int s0b = blockIdx.x * 128;
  const unsigned short* X = path ? Kb : Qb;
  const unsigned short* Y = path ? Qb : Kb;
  const unsigned short* YT = path ? QT : KT;   // f16
  const unsigned int* mp = path ? mp2 : mp1;
  unsigned short* outc = path ? c2 : c1;

  __shared__ __align__(16) unsigned short YS[64 * 72];    // Y chunk [j][d] bf16
  __shared__ __align__(16) unsigned short YTS[64 * 72];   // YT chunk [d][j] f16
  __shared__ unsigned int MW[128 * 33];                   // mask words for 128 rows

  const unsigned short* Xb = X + (size_t)bh * S * DK;
  const unsigned short* Yb = Y + (size_t)bh * S * DK;
  const unsigned short* YTb = YT + (size_t)bh * DK * S;
  const unsigned int* mb = mp + (size_t)bh * 32 * S;

  int tid = threadIdx.x;
  int w = tid >> 6, lane = tid & 63, lane15 = lane & 15, quad = lane >> 4;
  int s0w = s0b + w * 32;

  // stage mask words: MW[r][wd] = mb[wd*S + s0b + r], r in [0,128)
  {
    int wd = tid >> 3, rb = (tid & 7) * 16;
#pragma unroll
    for (int u = 0; u < 4; ++u) {
      uint4 v = *reinterpret_cast<const uint4*>(mb + (size_t)wd * S + s0b + rb + u * 4);
      MW[(rb + u * 4 + 0) * 33 + wd] = v.x;
      MW[(rb + u * 4 + 1) * 33 + wd] = v.y;
      MW[(rb + u * 4 + 2) * 33 + wd] = v.z;
      MW[(rb + u * 4 + 3) * 33 + wd] = v.w;
    }
  }

  // X fragments (A-operand, x32): 2 row-groups x 2 K-halves
  bf16x8 af[2][2];
#pragma unroll
  for (int rg = 0; rg < 2; ++rg) {
    af[rg][0] = ldfrag(Xb + (size_t)(s0w + rg * 16 + lane15) * DK + quad * 8);
    af[rg][1] = ldfrag(Xb + (size_t)(s0w + rg * 16 + lane15) * DK + 32 + quad * 8);
  }

  // identity for the transpose trick
  f16x4 iden;
#pragma unroll
  for (int i = 0; i < 4; ++i) iden[i] = (_Float16)((quad * 4 + i) == lane15 ? 1.0f : 0.0f);
  f32x4 zero4 = {};

  // staging: thread covers row sr4 (0..63), 16 cols at sc4
  int sr4 = tid >> 2, sc4 = (tid & 3) * 16;
  const unsigned short* gY = Yb + (size_t)sr4 * DK + sc4;        // + j0*DK
  const unsigned short* gYT = YTb + (size_t)sr4 * S + sc4;       // + j0
  uint4 y0 = *reinterpret_cast<const uint4*>(gY);
  uint4 y1 = *reinterpret_cast<const uint4*>(gY + 8);
  uint4 t0 = *reinterpret_cast<const uint4*>(gYT);
  uint4 t1 = *reinterpret_cast<const uint4*>(gYT + 8);

  f32x4 outa[2][4] = {};
  float lsum[2][4] = {};

  for (int jc = 0; jc < 16; ++jc) {
    __syncthreads();   // prior chunk frag reads complete
    *reinterpret_cast<uint4*>(&YS[sr4 * 72 + sc4]) = y0;
    *reinterpret_cast<uint4*>(&YS[sr4 * 72 + sc4 + 8]) = y1;
    *reinterpret_cast<uint4*>(&YTS[sr4 * 72 + sc4]) = t0;
    *reinterpret_cast<uint4*>(&YTS[sr4 * 72 + sc4 + 8]) = t1;
    {
      int jn = (jc + 1 < 16) ? (jc + 1) * 64 : jc * 64;   // clamped prefetch
      y0 = *reinterpret_cast<const uint4*>(gY + (size_t)jn * DK);
      y1 = *reinterpret_cast<const uint4*>(gY + (size_t)jn * DK + 8);
      t0 = *reinterpret_cast<const uint4*>(gYT + jn);
      t1 = *reinterpret_cast<const uint4*>(gYT + jn + 8);
    }
    __syncthreads();   // staging visible

    int j0 = jc * 64;
    int w0 = j0 >> 5;
    // scores: 4 subtiles of 16 j x 2 row groups
    f32x4 sc[2][4];
#pragma unroll
    for (int st = 0; st < 4; ++st) {
      bf16x8 b0 = ldfrag(&YS[(st * 16 + lane15) * 72 + quad * 8]);
      bf16x8 b1 = ldfrag(&YS[(st * 16 + lane15) * 72 + 32 + quad * 8]);
#pragma unroll
      for (int rg = 0; rg < 2; ++rg) {
        f32x4 a = {};
        a = __builtin_amdgcn_mfma_f32_16x16x32_bf16(af[rg][0], b0, a, 0, 0, 0);
        a = __builtin_amdgcn_mfma_f32_16x16x32_bf16(af[rg][1], b1, a, 0, 0, 0);
        sc[rg][st] = a;
      }
    }
    // mask + exp (no max subtraction) + row-sum; pack P into f16 C-frags
    f16x4 pfa[2][4];
#pragma unroll
    for (int rg = 0; rg < 2; ++rg) {
      unsigned int mw0[4], mw1[4];
#pragma unroll
      for (int reg = 0; reg < 4; ++reg) {
        int r = w * 32 + rg * 16 + quad * 4 + reg;
        mw0[reg] = MW[r * 33 + w0];
        mw1[reg] = MW[r * 33 + w0 + 1];
      }
#pragma unroll
      for (int st = 0; st < 4; ++st) {
        unsigned int sh = (unsigned)((st & 1) * 16 + lane15);
#pragma unroll
        for (int reg = 0; reg < 4; ++reg) {
          unsigned int wd = (st < 2) ? mw0[reg] : mw1[reg];
          float e = __expf(sc[rg][st][reg] * 0.125f);
          float p = ((wd >> sh) & 1u) ? 0.f : e;
          lsum[rg][reg] += p;
          pfa[rg][st][reg] = (_Float16)p;
        }
      }
    }
    // PV: transpose P subtiles in-register, then f16 x16 MFMA against YTS b64 frags
#pragma unroll
    for (int st = 0; st < 4; ++st) {
      f16x4 ptb[2];
#pragma unroll
      for (int rg = 0; rg < 2; ++rg) {
        f32x4 pt = __builtin_amdgcn_mfma_f32_16x16x16f16(pfa[rg][st], iden, zero4, 0, 0, 0);
        f16x4 pb;
#pragma unroll
        for (int i = 0; i < 4; ++i) pb[i] = (_Float16)pt[i];
        ptb[rg] = pb;
      }
#pragma unroll
      for (int dt = 0; dt < 4; ++dt) {
        uint2 q = *reinterpret_cast<const uint2*>(&YTS[(dt * 16 + lane15) * 72 + st * 16 + quad * 4]);
        f16x4 yb = __builtin_bit_cast(f16x4, q);
#pragma unroll
        for (int rg = 0; rg < 2; ++rg)
          outa[rg][dt] = __builtin_amdgcn_mfma_f32_16x16x16f16(ptb[rg], yb, outa[rg][dt], 0, 0, 0);
      }
    }
  }

  // reduce row sums across the 16 lanes of each quad-row group
#pragma unroll
  for (int rg = 0; rg < 2; ++rg)
#pragma unroll
    for (int reg = 0; reg < 4; ++reg) {
#pragma unroll
      for (int m = 1; m < 16; m <<= 1) lsum[rg][reg] += __shfl_xor(lsum[rg][reg], m);
      lsum[rg][reg] = 1.0f / lsum[rg][reg];
    }
  int b = bh / NH, h = bh % NH;
#pragma unroll
  for (int rg = 0; rg < 2; ++rg)
#pragma unroll
    for (int dt = 0; dt < 4; ++dt)
#pragma unroll
      for (int reg = 0; reg < 4; ++reg) {
        float v = outa[rg][dt][reg] * lsum[rg][reg];
        int srow = s0w + rg * 16 + quad * 4 + reg;
        size_t idx = ((size_t)(b * S) + srow) * DMODEL + h * DK + dt * 16 + lane15;
        outc[idx] = f2bf(v);
      }
}

// ---------------- LayerNorm over 768, one block per row ----------------
__global__ __launch_bounds__(256) void k_ln(const float* __restrict__ f1, const float* __restrict__ f2,
                                            const float* __restrict__ g1, const float* __restrict__ b1,
                                            const float* __restrict__ g2, const float* __restrict__ b2,
                                            float* __restrict__ out) {
  int rowg = blockIdx.x;
  int sel = rowg >> 12;
  int row = rowg & 4095;
  const float* in = sel ? f2 : f1;
  const float* g = sel ? g2 : g1;
  const float* be = sel ? b2 : b1;
  int tid = threadIdx.x;
  const float* p = in + (size_t)row * DMODEL;
  float x0 = p[tid], x1 = p[tid + 256], x2 = p[tid + 512];
  float s = x0 + x1 + x2;
  float ss = x0 * x0 + x1 * x1 + x2 * x2;
#pragma unroll
  for (int m = 1; m < 64; m <<= 1) { s += __shfl_xor(s, m); ss += __shfl_xor(ss, m); }
  __shared__ float ps[4], pss[4];
  int w = tid >> 6;
  if ((tid & 63) == 0) { ps[w] = s; pss[w] = ss; }
  __syncthreads();
  s = ps[0] + ps[1] + ps[2] + ps[3];
  ss = pss[0] + pss[1] + pss[2] + pss[3];
  float mu = s * (1.0f / 768.0f);
  float var = ss * (1.0f / 768.0f) - mu * mu;
  float rstd = rsqrtf(var + 1e-5f);
  float* o = out + ((size_t)sel * M4 + row) * DMODEL;
  o[tid] = (x0 - mu) * rstd * g[tid] + be[tid];
  o[tid + 256] = (x1 - mu) * rstd * g[tid + 256] + be[tid + 256];
  o[tid + 512] = (x2 - mu) * rstd * g[tid + 512] + be[tid + 512];
}

extern "C" void kernel_launch(void* const* d_in, const int* in_sizes, int n_in,
                              void* d_out, int out_size, void* d_ws, size_t ws_size,
                              hipStream_t stream) {
  const float* pro1 = (const float*)d_in[0];
  const float* pro2 = (const float*)d_in[1];
  const int* mask = (const int*)d_in[2];
  const float* WQ = (const float*)d_in[3];
  const float* WK = (const float*)d_in[4];
  const float* FC1 = (const float*)d_in[5];
  const float* g1 = (const float*)d_in[6];
  const float* b1 = (const float*)d_in[7];
  const float* g2 = (const float*)d_in[8];
  const float* b2 = (const float*)d_in[9];
  float* out = (float*)d_out;
  char* ws = (char*)d_ws;

  // workspace layout (bytes)
  float* f1 = (float*)(ws + 0);                               // 12582912
  unsigned short* wqt = (unsigned short*)(ws + 12582912);     // 1179648
  unsigned short* wkt = (unsigned short*)(ws + 13762560);     // 1179648
  unsigned short* fc1t = (unsigned short*)(ws + 14942208);    // 1179648
  unsigned short* Qb = (unsigned short*)(ws + 16121856);      // 6291456 bf16
  unsigned short* Kb = (unsigned short*)(ws + 22413312);      // 6291456 bf16
  unsigned short* QT = (unsigned short*)(ws + 28704768);      // 6291456 f16
  unsigned short* KT = (unsigned short*)(ws + 34996224);      // 6291456 f16
  unsigned int* mp1 = (unsigned int*)(ws + 41287680);         // 6291456
  unsigned int* mp2 = (unsigned int*)(ws + 47579136);         // 6291456
  float* f2 = (float*)(ws + 41287680);                        // overlays mp1/mp2 (dead after attn)
  unsigned short* c1 = (unsigned short*)(ws + 53870592);      // 6291456
  unsigned short* c2 = (unsigned short*)(ws + 60162048);      // 6291456
  // total ~66.5 MB

  k_transpose<<<dim3(24, 24, 3), 256, 0, stream>>>(WQ, WK, FC1, wqt, wkt, fc1t);
  k_pack<<<dim3(64, BH), 256, 0, stream>>>(mask, mp1, mp2);
  k_gemm128<<<dim3(32, 6, 2), 256, 0, stream>>>(0, pro1, pro2, nullptr, nullptr, wqt, wkt,
                                                Qb, Kb, QT, KT, nullptr, nullptr);
  k_attn<<<dim3(8, BH, 2), 256, 0, stream>>>(Qb, Kb, QT, KT, mp1, mp2, c1, c2);
  k_gemm128<<<dim3(32, 6, 2), 256, 0, stream>>>(1, nullptr, nullptr, c1, c2, fc1t, fc1t,
                                                nullptr, nullptr, nullptr, nullptr, f1, f2);
  k_ln<<<8192, 256, 0, stream>>>(f1, f2, g1, b1, g2, b2, out);
}

// Round 5
// 474.413 us; speedup vs baseline: 1.0117x; 1.0117x over previous
//
#include <hip/hip_runtime.h>
#include <hip/hip_bf16.h>
#include <stdint.h>

// Problem constants
#define S 1024
#define DMODEL 768
#define NH 12
#define DK 64
#define BB 4
#define BH 48      // BB*NH
#define M4 4096    // BB*S

typedef __attribute__((ext_vector_type(8))) short bf16x8;
typedef __attribute__((ext_vector_type(4))) float f32x4;
typedef __attribute__((ext_vector_type(4))) _Float16 f16x4;
typedef __attribute__((ext_vector_type(8))) _Float16 f16x8;

static __device__ __forceinline__ unsigned short f2bf(float f) {
  unsigned int u = __float_as_uint(f);
  unsigned int r = u + 0x7FFFu + ((u >> 16) & 1u);   // RNE
  return (unsigned short)(r >> 16);
}
static __device__ __forceinline__ unsigned int pk2(float a, float b) {
  return (unsigned int)f2bf(a) | ((unsigned int)f2bf(b) << 16);
}
static __device__ __forceinline__ bf16x8 ldfrag(const unsigned short* p) {
  uint4 q = *reinterpret_cast<const uint4*>(p);
  return __builtin_bit_cast(bf16x8, q);
}
static __device__ __forceinline__ f16x8 ldfragh(const unsigned short* p) {
  uint4 q = *reinterpret_cast<const uint4*>(p);
  return __builtin_bit_cast(f16x8, q);
}
static __device__ __forceinline__ unsigned short h2u(_Float16 h) {
  return __builtin_bit_cast(unsigned short, h);
}

// ---------------- W [k][n] f32 -> Wt [n][k] bf16 (768x768) ----------------
__global__ __launch_bounds__(256) void k_transpose(const float* w0, const float* w1, const float* w2,
                                                   unsigned short* o0, unsigned short* o1, unsigned short* o2) {
  const float* in = blockIdx.z == 0 ? w0 : (blockIdx.z == 1 ? w1 : w2);
  unsigned short* out = blockIdx.z == 0 ? o0 : (blockIdx.z == 1 ? o1 : o2);
  __shared__ float tile[32][33];
  int n0 = blockIdx.x * 32, k0 = blockIdx.y * 32;
  int tid = threadIdx.x;
  int r = tid >> 3, c = (tid & 7) * 4;
  float4 v = *reinterpret_cast<const float4*>(in + (size_t)(k0 + r) * DMODEL + n0 + c);
  tile[r][c] = v.x; tile[r][c + 1] = v.y; tile[r][c + 2] = v.z; tile[r][c + 3] = v.w;
  __syncthreads();
  ushort4 o;
  o.x = f2bf(tile[c + 0][r]);
  o.y = f2bf(tile[c + 1][r]);
  o.z = f2bf(tile[c + 2][r]);
  o.w = f2bf(tile[c + 3][r]);
  *reinterpret_cast<ushort4*>(out + (size_t)(n0 + r) * DMODEL + k0 + c) = o;
}

// ---------------- mask [BH][t][s] int32 -> bit array, direct orientation only ----------------
// mp2[bh][wd=s>>5][t] bit(s&31) = mask[t][s].  Pure stream: coalesced reads + ballot.
__global__ __launch_bounds__(256) void k_pack(const int* __restrict__ mask,
                                              unsigned int* __restrict__ mp2) {
  int bh = blockIdx.y;
  int w = threadIdx.x >> 6, lane = threadIdx.x & 63;
  int tile = blockIdx.x * 4 + w;          // 0..255
  int ti = tile >> 4, tj = tile & 15;
  int t0 = ti * 64, s0 = tj * 64;
  const int* mb = mask + (size_t)bh * S * S;
  unsigned long long rowword = 0;
#pragma unroll 8
  for (int r = 0; r < 64; ++r) {
    int v = mb[(size_t)(t0 + r) * S + s0 + lane];
    unsigned long long b = __ballot(v != 0);
    if (lane == r) rowword = b;           // lane r holds bits over s for row t0+r
  }
  unsigned int* p2 = mp2 + (size_t)bh * 32 * S;
  p2[((s0 >> 5) + 0) * S + t0 + lane] = (unsigned int)rowword;
  p2[((s0 >> 5) + 1) * S + t0 + lane] = (unsigned int)(rowword >> 32);
}

// ---------------- 128x128-tile bf16 GEMM: C[4096x768] = A[4096x768] * Bt^T ----------------
// mode 0: A f32 (converted during staging); writes Q/K [BH][S][DK] f16 AND
//         transposed [BH][DK][S] f16, both via vectorized dual-layout epilogue.
// mode 1: A bf16; writes f32 [4096][768] (pre-LayerNorm).
__global__ __launch_bounds__(256, 2) void k_gemm128(
    int mode,
    const float* __restrict__ Af0, const float* __restrict__ Af1,
    const unsigned short* __restrict__ Ab0, const unsigned short* __restrict__ Ab1,
    const unsigned short* __restrict__ Bt0, const unsigned short* __restrict__ Bt1,
    unsigned short* __restrict__ oQ0, unsigned short* __restrict__ oQ1,
    unsigned short* __restrict__ oT0, unsigned short* __restrict__ oT1,
    float* __restrict__ oF0, float* __restrict__ oF1) {
  const float* Af = blockIdx.z ? Af1 : Af0;
  const unsigned short* Ab = blockIdx.z ? Ab1 : Ab0;
  const unsigned short* Bt = blockIdx.z ? Bt1 : Bt0;
  __shared__ __align__(16) unsigned short As[128 * 72];   // 18432 B
  __shared__ __align__(16) unsigned short Bs[128 * 72];   // 18432 B
  int tid = threadIdx.x;
  int m0 = blockIdx.x * 128, n0 = blockIdx.y * 128;
  int w = tid >> 6, lane = tid & 63, lane15 = lane & 15, quad = lane >> 4;
  int row0 = (w >> 1) * 64, col0 = (w & 1) * 64;
  f32x4 acc[4][4] = {};
  int sr = tid >> 2, sc = (tid & 3) * 16;
  const unsigned short* gB0 = Bt + (size_t)(n0 + sr) * DMODEL + sc;
  const unsigned short* gB1 = Bt + (size_t)(n0 + 64 + sr) * DMODEL + sc;
  uint4 vb[2][2];
  vb[0][0] = *reinterpret_cast<const uint4*>(gB0);
  vb[0][1] = *reinterpret_cast<const uint4*>(gB0 + 8);
  vb[1][0] = *reinterpret_cast<const uint4*>(gB1);
  vb[1][1] = *reinterpret_cast<const uint4*>(gB1 + 8);
  const float* gAf0 = Af + (size_t)(m0 + sr) * DMODEL + sc;
  const float* gAf1 = Af + (size_t)(m0 + 64 + sr) * DMODEL + sc;
  const unsigned short* gAb0 = Ab + (size_t)(m0 + sr) * DMODEL + sc;
  const unsigned short* gAb1 = Ab + (size_t)(m0 + 64 + sr) * DMODEL + sc;
  float4 fa[2][4];
  uint4 va[2][2];
  if (mode == 0) {
#pragma unroll
    for (int g = 0; g < 4; ++g) fa[0][g] = *reinterpret_cast<const float4*>(gAf0 + g * 4);
#pragma unroll
    for (int g = 0; g < 4; ++g) fa[1][g] = *reinterpret_cast<const float4*>(gAf1 + g * 4);
  } else {
    va[0][0] = *reinterpret_cast<const uint4*>(gAb0);
    va[0][1] = *reinterpret_cast<const uint4*>(gAb0 + 8);
    va[1][0] = *reinterpret_cast<const uint4*>(gAb1);
    va[1][1] = *reinterpret_cast<const uint4*>(gAb1 + 8);
  }
  for (int kc = 0; kc < 12; ++kc) {
    __syncthreads();   // prior iter frag reads complete
    if (mode == 0) {
#pragma unroll
      for (int h2 = 0; h2 < 2; ++h2) {
        uint4 u0, u1;
        u0.x = pk2(fa[h2][0].x, fa[h2][0].y); u0.y = pk2(fa[h2][0].z, fa[h2][0].w);
        u0.z = pk2(fa[h2][1].x, fa[h2][1].y); u0.w = pk2(fa[h2][1].z, fa[h2][1].w);
        u1.x = pk2(fa[h2][2].x, fa[h2][2].y); u1.y = pk2(fa[h2][2].z, fa[h2][2].w);
        u1.z = pk2(fa[h2][3].x, fa[h2][3].y); u1.w = pk2(fa[h2][3].z, fa[h2][3].w);
        *reinterpret_cast<uint4*>(&As[(h2 * 64 + sr) * 72 + sc]) = u0;
        *reinterpret_cast<uint4*>(&As[(h2 * 64 + sr) * 72 + sc + 8]) = u1;
      }
    } else {
#pragma unroll
      for (int h2 = 0; h2 < 2; ++h2) {
        *reinterpret_cast<uint4*>(&As[(h2 * 64 + sr) * 72 + sc]) = va[h2][0];
        *reinterpret_cast<uint4*>(&As[(h2 * 64 + sr) * 72 + sc + 8]) = va[h2][1];
      }
    }
#pragma unroll
    for (int h2 = 0; h2 < 2; ++h2) {
      *reinterpret_cast<uint4*>(&Bs[(h2 * 64 + sr) * 72 + sc]) = vb[h2][0];
      *reinterpret_cast<uint4*>(&Bs[(h2 * 64 + sr) * 72 + sc + 8]) = vb[h2][1];
    }
    if (kc < 11) {
      int k0 = (kc + 1) * 64;
      if (mode == 0) {
#pragma unroll
        for (int g = 0; g < 4; ++g) fa[0][g] = *reinterpret_cast<const float4*>(gAf0 + k0 + g * 4);
#pragma unroll
        for (int g = 0; g < 4; ++g) fa[1][g] = *reinterpret_cast<const float4*>(gAf1 + k0 + g * 4);
      } else {
        va[0][0] = *reinterpret_cast<const uint4*>(gAb0 + k0);
        va[0][1] = *reinterpret_cast<const uint4*>(gAb0 + k0 + 8);
        va[1][0] = *reinterpret_cast<const uint4*>(gAb1 + k0);
        va[1][1] = *reinterpret_cast<const uint4*>(gAb1 + k0 + 8);
      }
      vb[0][0] = *reinterpret_cast<const uint4*>(gB0 + k0);
      vb[0][1] = *reinterpret_cast<const uint4*>(gB0 + k0 + 8);
      vb[1][0] = *reinterpret_cast<const uint4*>(gB1 + k0);
      vb[1][1] = *reinterpret_cast<const uint4*>(gB1 + k0 + 8);
    }
    __syncthreads();
#pragma unroll
    for (int ks = 0; ks < 2; ++ks) {
      int kk = ks * 32 + quad * 8;
      bf16x8 a[4], b[4];
#pragma unroll
      for (int i = 0; i < 4; ++i) a[i] = ldfrag(&As[(row0 + i * 16 + lane15) * 72 + kk]);
#pragma unroll
      for (int j = 0; j < 4; ++j) b[j] = ldfrag(&Bs[(col0 + j * 16 + lane15) * 72 + kk]);
#pragma unroll
      for (int i = 0; i < 4; ++i)
#pragma unroll
        for (int j = 0; j < 4; ++j)
          acc[i][j] = __builtin_amdgcn_mfma_f32_16x16x32_bf16(a[i], b[j], acc[i][j], 0, 0, 0);
    }
  }
  if (mode == 0) {
    unsigned short* out = blockIdx.z ? oQ1 : oQ0;
    unsigned short* outT = blockIdx.z ? oT1 : oT0;
    f16x4 iden;
#pragma unroll
    for (int i = 0; i < 4; ++i) iden[i] = (_Float16)((quad * 4 + i) == lane15 ? 1.0f : 0.0f);
    f32x4 zero4 = {};
#pragma unroll
    for (int i = 0; i < 4; ++i)
#pragma unroll
      for (int j = 0; j < 4; ++j) {
        f16x4 cf;
#pragma unroll
        for (int reg = 0; reg < 4; ++reg) cf[reg] = (_Float16)acc[i][j][reg];
        f32x4 tq = __builtin_amdgcn_mfma_f32_16x16x16f16(cf, iden, zero4, 0, 0, 0);
        {   // Qb store: tq regs = 4 consecutive d, fixed s -> ushort4
          int m = m0 + row0 + i * 16 + lane15;
          int n = n0 + col0 + j * 16 + quad * 4;
          int b = m >> 10, s = m & 1023, h = n >> 6, d = n & 63;
          ushort4 o;
          o.x = h2u((_Float16)tq[0]); o.y = h2u((_Float16)tq[1]);
          o.z = h2u((_Float16)tq[2]); o.w = h2u((_Float16)tq[3]);
          *reinterpret_cast<ushort4*>(&out[(((size_t)(b * NH + h)) * S + s) * DK + d]) = o;
        }
        {   // QT store: acc regs = 4 consecutive s, fixed d -> ushort4
          int n = n0 + col0 + j * 16 + lane15;
          int m = m0 + row0 + i * 16 + quad * 4;
          int b = m >> 10, s = m & 1023, h = n >> 6, d = n & 63;
          ushort4 o;
          o.x = h2u((_Float16)acc[i][j][0]); o.y = h2u((_Float16)acc[i][j][1]);
          o.z = h2u((_Float16)acc[i][j][2]); o.w = h2u((_Float16)acc[i][j][3]);
          *reinterpret_cast<ushort4*>(&outT[(((size_t)(b * NH + h)) * DK + d) * S + s]) = o;
        }
      }
  } else {
    float* out = blockIdx.z ? oF1 : oF0;
#pragma unroll
    for (int i = 0; i < 4; ++i)
#pragma unroll
      for (int j = 0; j < 4; ++j)
#pragma unroll
        for (int reg = 0; reg < 4; ++reg) {
          int m = m0 + row0 + i * 16 + quad * 4 + reg;
          int n = n0 + col0 + j * 16 + lane15;
          out[(size_t)m * DMODEL + n] = acc[i][j][reg];
        }
  }
}

// ---------------- fused dual-path attention: operand-swapped S^T, no P round-trip ----------------
// Block = (bh, path, 128 rows); wave w owns rows [s0b+w*32, +32) (2 groups of 16).
// Per 64-j chunk: stage Y [j][d] + YT [d][j] (f16) + 1KB mask words.
// QK: S^T frags via mfma(A=Y, B=Xfrag) -> C(row=j,col=s) == x16 A-operand layout.
// exp w/o max-subtraction (masked -> exact 0), PV via 16x16x16 f16 MFMA. Zero P LDS.
__global__ __launch_bounds__(256, 3) void k_attn(
    const unsigned short* __restrict__ Qb, const unsigned short* __restrict__ Kb,
    const unsigned short* __restrict__ QT, const unsigned short* __restrict__ KT,
    const unsigned int* __restrict__ mp2,
    unsigned short* __restrict__ c1, unsigned short* __restrict__ c2) {
  int bh = blockIdx.y, path = blockIdx.z;
  int s0b = blockIdx.x * 128;
  const unsigned short* X = path ? Kb : Qb;
  const unsigned short* Y = path ? Qb : Kb;
  const unsigned short* YT = path ? QT : KT;
  unsigned short* outc = path ? c2 : c1;

  __shared__ __align__(16) unsigned short YS[64 * 72];    // Y chunk [j][d] f16
  __shared__ __align__(16) unsigned short YTS[64 * 72];   // YT chunk [d][j] f16
  __shared__ unsigned int MWS[256];                       // mask words for this chunk

  const unsigned short* Xb = X + (size_t)bh * S * DK;
  const unsigned short* Yb = Y + (size_t)bh * S * DK;
  const unsigned short* YTb = YT + (size_t)bh * DK * S;
  const unsigned int* mbg = mp2 + (size_t)bh * 32 * S;

  int tid = threadIdx.x;
  int w = tid >> 6, lane = tid & 63, lane15 = lane & 15, quad = lane >> 4;
  int s0w = s0b + w * 32;

  // X fragments double as MFMA B-operands (B[k=d][n=s]) for the swapped QK
  f16x8 xf[2][2];
#pragma unroll
  for (int rg = 0; rg < 2; ++rg) {
    xf[rg][0] = ldfragh(Xb + (size_t)(s0w + rg * 16 + lane15) * DK + quad * 8);
    xf[rg][1] = ldfragh(Xb + (size_t)(s0w + rg * 16 + lane15) * DK + 32 + quad * 8);
  }

  // staging: thread covers row sr4 (0..63), 16 cols at sc4
  int sr4 = tid >> 2, sc4 = (tid & 3) * 16;
  const unsigned short* gY = Yb + (size_t)sr4 * DK + sc4;
  const unsigned short* gYT = YTb + (size_t)sr4 * S + sc4;
  uint4 y0 = *reinterpret_cast<const uint4*>(gY);
  uint4 y1 = *reinterpret_cast<const uint4*>(gY + 8);
  uint4 t0 = *reinterpret_cast<const uint4*>(gYT);
  uint4 t1 = *reinterpret_cast<const uint4*>(gYT + 8);
  // mask-word prefetch (both paths read mp2 direct orientation)
  int mws_idx = (path == 0) ? ((tid & 63) * 4 + (tid >> 6)) : ((tid & 127) * 2 + (tid >> 7));
  unsigned int mwv = (path == 0)
      ? mbg[((size_t)((s0b >> 5) + (tid >> 6))) * S + (tid & 63)]
      : mbg[((size_t)(tid >> 7)) * S + s0b + (tid & 127)];

  f32x4 outa[2][4] = {};
  float lsum[2] = {0.f, 0.f};

  for (int jc = 0; jc < 16; ++jc) {
    __syncthreads();   // prior chunk frag reads complete
    *reinterpret_cast<uint4*>(&YS[sr4 * 72 + sc4]) = y0;
    *reinterpret_cast<uint4*>(&YS[sr4 * 72 + sc4 + 8]) = y1;
    *reinterpret_cast<uint4*>(&YTS[sr4 * 72 + sc4]) = t0;
    *reinterpret_cast<uint4*>(&YTS[sr4 * 72 + sc4 + 8]) = t1;
    MWS[mws_idx] = mwv;
    {
      int jn = (jc + 1 < 16) ? (jc + 1) * 64 : jc * 64;   // clamped prefetch
      y0 = *reinterpret_cast<const uint4*>(gY + (size_t)jn * DK);
      y1 = *reinterpret_cast<const uint4*>(gY + (size_t)jn * DK + 8);
      t0 = *reinterpret_cast<const uint4*>(gYT + jn);
      t1 = *reinterpret_cast<const uint4*>(gYT + jn + 8);
      mwv = (path == 0)
          ? mbg[((size_t)((s0b >> 5) + (tid >> 6))) * S + jn + (tid & 63)]
          : mbg[((size_t)((jn >> 5) + (tid >> 7))) * S + s0b + (tid & 127)];
    }
    __syncthreads();   // staging visible

    // swapped QK: S^T[j][s] frags, C(row=j=quad*4+reg, col=s=lane15)
    f32x4 scv[4][2];
#pragma unroll
    for (int st = 0; st < 4; ++st) {
      f16x8 a0 = ldfragh(&YS[(st * 16 + lane15) * 72 + quad * 8]);
      f16x8 a1 = ldfragh(&YS[(st * 16 + lane15) * 72 + 32 + quad * 8]);
#pragma unroll
      for (int rg = 0; rg < 2; ++rg) {
        f32x4 v = {};
        v = __builtin_amdgcn_mfma_f32_16x16x32_f16(a0, xf[rg][0], v, 0, 0, 0);
        v = __builtin_amdgcn_mfma_f32_16x16x32_f16(a1, xf[rg][1], v, 0, 0, 0);
        scv[st][rg] = v;
      }
    }
    // mask + exp; P^T frags are directly x16 A-operands
    f16x4 pfa[4][2];
    if (path == 0) {
      // word = MWS[jlocal*4 + w], bit = rg*16 + lane15
#pragma unroll
      for (int st = 0; st < 4; ++st)
#pragma unroll
        for (int reg = 0; reg < 4; ++reg) {
          unsigned int wdv = MWS[(st * 16 + quad * 4 + reg) * 4 + w];
#pragma unroll
          for (int rg = 0; rg < 2; ++rg) {
            float e = __expf(scv[st][rg][reg] * 0.125f);
            float p = ((wdv >> (unsigned)(rg * 16 + lane15)) & 1u) ? 0.f : e;
            lsum[rg] += p;
            pfa[st][rg][reg] = (_Float16)p;
          }
        }
    } else {
      // word = MWS[row*2 + (st>>1)], bit = (st&1)*16 + quad*4 + reg
#pragma unroll
      for (int rg = 0; rg < 2; ++rg) {
        unsigned int wv0 = MWS[(w * 32 + rg * 16 + lane15) * 2 + 0];
        unsigned int wv1 = MWS[(w * 32 + rg * 16 + lane15) * 2 + 1];
#pragma unroll
        for (int st = 0; st < 4; ++st) {
          unsigned int wdv = (st < 2) ? wv0 : wv1;
#pragma unroll
          for (int reg = 0; reg < 4; ++reg) {
            unsigned int sh = (unsigned)((st & 1) * 16 + quad * 4 + reg);
            float e = __expf(scv[st][rg][reg] * 0.125f);
            float p = ((wdv >> sh) & 1u) ? 0.f : e;
            lsum[rg] += p;
            pfa[st][rg][reg] = (_Float16)p;
          }
        }
      }
    }
    // PV: outa[rg][dsub] += P^T_frag (A) x Y (B from YTS, b64 reads)
#pragma unroll
    for (int st = 0; st < 4; ++st)
#pragma unroll
      for (int dsub = 0; dsub < 4; ++dsub) {
        uint2 q = *reinterpret_cast<const uint2*>(&YTS[(dsub * 16 + lane15) * 72 + st * 16 + quad * 4]);
        f16x4 yb = __builtin_bit_cast(f16x4, q);
#pragma unroll
        for (int rg = 0; rg < 2; ++rg)
          outa[rg][dsub] = __builtin_amdgcn_mfma_f32_16x16x16f16(pfa[st][rg], yb, outa[rg][dsub], 0, 0, 0);
      }
  }

  // row sums: lane holds partial for row (rg, lane15) over its j cols; reduce across quads
#pragma unroll
  for (int rg = 0; rg < 2; ++rg) {
    lsum[rg] += __shfl_xor(lsum[rg], 16);
    lsum[rg] += __shfl_xor(lsum[rg], 32);
  }
  float rinv[2][4];
#pragma unroll
  for (int rg = 0; rg < 2; ++rg)
#pragma unroll
    for (int reg = 0; reg < 4; ++reg)
      rinv[rg][reg] = 1.0f / __shfl(lsum[rg], quad * 4 + reg);

  int b = bh / NH, h = bh % NH;
#pragma unroll
  for (int rg = 0; rg < 2; ++rg)
#pragma unroll
    for (int dsub = 0; dsub < 4; ++dsub)
#pragma unroll
      for (int reg = 0; reg < 4; ++reg) {
        float v = outa[rg][dsub][reg] * rinv[rg][reg];
        int srow = s0w + rg * 16 + quad * 4 + reg;
        size_t idx = ((size_t)(b * S) + srow) * DMODEL + h * DK + dsub * 16 + lane15;
        outc[idx] = f2bf(v);
      }
}

// ---------------- LayerNorm over 768, one block per row ----------------
__global__ __launch_bounds__(256) void k_ln(const float* __restrict__ f1, const float* __restrict__ f2,
                                            const float* __restrict__ g1, const float* __restrict__ b1,
                                            const float* __restrict__ g2, const float* __restrict__ b2,
                                            float* __restrict__ out) {
  int rowg = blockIdx.x;
  int sel = rowg >> 12;
  int row = rowg & 4095;
  const float* in = sel ? f2 : f1;
  const float* g = sel ? g2 : g1;
  const float* be = sel ? b2 : b1;
  int tid = threadIdx.x;
  const float* p = in + (size_t)row * DMODEL;
  float x0 = p[tid], x1 = p[tid + 256], x2 = p[tid + 512];
  float s = x0 + x1 + x2;
  float ss = x0 * x0 + x1 * x1 + x2 * x2;
#pragma unroll
  for (int m = 1; m < 64; m <<= 1) { s += __shfl_xor(s, m); ss += __shfl_xor(ss, m); }
  __shared__ float ps[4], pss[4];
  int w = tid >> 6;
  if ((tid & 63) == 0) { ps[w] = s; pss[w] = ss; }
  __syncthreads();
  s = ps[0] + ps[1] + ps[2] + ps[3];
  ss = pss[0] + pss[1] + pss[2] + pss[3];
  float mu = s * (1.0f / 768.0f);
  float var = ss * (1.0f / 768.0f) - mu * mu;
  float rstd = rsqrtf(var + 1e-5f);
  float* o = out + ((size_t)sel * M4 + row) * DMODEL;
  o[tid] = (x0 - mu) * rstd * g[tid] + be[tid];
  o[tid + 256] = (x1 - mu) * rstd * g[tid + 256] + be[tid + 256];
  o[tid + 512] = (x2 - mu) * rstd * g[tid + 512] + be[tid + 512];
}

extern "C" void kernel_launch(void* const* d_in, const int* in_sizes, int n_in,
                              void* d_out, int out_size, void* d_ws, size_t ws_size,
                              hipStream_t stream) {
  const float* pro1 = (const float*)d_in[0];
  const float* pro2 = (const float*)d_in[1];
  const int* mask = (const int*)d_in[2];
  const float* WQ = (const float*)d_in[3];
  const float* WK = (const float*)d_in[4];
  const float* FC1 = (const float*)d_in[5];
  const float* g1 = (const float*)d_in[6];
  const float* b1 = (const float*)d_in[7];
  const float* g2 = (const float*)d_in[8];
  const float* b2 = (const float*)d_in[9];
  float* out = (float*)d_out;
  char* ws = (char*)d_ws;

  // workspace layout (bytes)
  float* f1 = (float*)(ws + 0);                               // 12582912
  unsigned short* wqt = (unsigned short*)(ws + 12582912);     // 1179648
  unsigned short* wkt = (unsigned short*)(ws + 13762560);     // 1179648
  unsigned short* fc1t = (unsigned short*)(ws + 14942208);    // 1179648
  unsigned short* Qb = (unsigned short*)(ws + 16121856);      // 6291456 f16 [bh][s][d]
  unsigned short* Kb = (unsigned short*)(ws + 22413312);      // 6291456 f16
  unsigned short* QT = (unsigned short*)(ws + 28704768);      // 6291456 f16 [bh][d][s]
  unsigned short* KT = (unsigned short*)(ws + 34996224);      // 6291456 f16
  unsigned int* mp2 = (unsigned int*)(ws + 41287680);         // 6291456
  float* f2 = (float*)(ws + 47579136);                        // 12582912
  unsigned short* c1 = (unsigned short*)(ws + 60162048);      // 6291456 bf16
  unsigned short* c2 = (unsigned short*)(ws + 66453504);      // 6291456 bf16
  // total ~72.7 MB

  k_transpose<<<dim3(24, 24, 3), 256, 0, stream>>>(WQ, WK, FC1, wqt, wkt, fc1t);
  k_pack<<<dim3(64, BH), 256, 0, stream>>>(mask, mp2);
  k_gemm128<<<dim3(32, 6, 2), 256, 0, stream>>>(0, pro1, pro2, nullptr, nullptr, wqt, wkt,
                                                Qb, Kb, QT, KT, nullptr, nullptr);
  k_attn<<<dim3(8, BH, 2), 256, 0, stream>>>(Qb, Kb, QT, KT, mp2, c1, c2);
  k_gemm128<<<dim3(32, 6, 2), 256, 0, stream>>>(1, nullptr, nullptr, c1, c2, fc1t, fc1t,
                                                nullptr, nullptr, nullptr, nullptr, f1, f2);
  k_ln<<<8192, 256, 0, stream>>>(f1, f2, g1, b1, g2, b2, out);
}